// Round 12
// baseline (189.071 us; speedup 1.0000x reference)
//
#include <hip/hip_runtime.h>
#include <cstdint>
#include <cstddef>

#define HID 1024
#define NH 16
#define HD 64
#define SEQ 2048
#define BATCH 2

typedef __attribute__((ext_vector_type(8))) short bf16x8;
typedef __attribute__((ext_vector_type(4))) short bf16x4;
typedef bf16x8 __attribute__((may_alias)) bf16x8_ma;
typedef bf16x4 __attribute__((may_alias)) bf16x4_ma;
typedef uint4 __attribute__((may_alias)) uint4_ma;
typedef __attribute__((ext_vector_type(4))) float f32x4;

__device__ __forceinline__ unsigned short f2bf(float f){
  unsigned u = __builtin_bit_cast(unsigned, f);
  u += 0x7fffu + ((u >> 16) & 1u);
  return (unsigned short)(u >> 16);
}

__device__ __forceinline__ unsigned cvtpk_bf16(float lo, float hi){
  unsigned r;
  asm("v_cvt_pk_bf16_f32 %0, %1, %2" : "=v"(r) : "v"(lo), "v"(hi));
  return r;
}

// async global->LDS, 16B per lane. LDS dest is wave-uniform base; HW adds lane*16B.
__device__ __forceinline__ void gll(const unsigned short* g, unsigned short* l){
  __builtin_amdgcn_global_load_lds(
      (const __attribute__((address_space(1))) unsigned int*)(g),
      (__attribute__((address_space(3))) unsigned int*)(l),
      16, 0, 0);
}

// Chunk-XOR LDS swizzle: data (row r, 16B-chunk c) lives at chunk-slot c^((r>>1)&3).
// Staging keeps the LDS dest linear (gll requirement) and pre-swizzles the GLOBAL
// source chunk; every fragment read applies the same XOR. 8-way -> 2-way (free).

// ---------------- fp32 -> bf16 conversion of x and the 4 weights ----------------
__global__ __launch_bounds__(256) void cvt_all(
    const float* __restrict__ x,  const float* __restrict__ wq,
    const float* __restrict__ wk, const float* __restrict__ wv,
    const float* __restrict__ wo,
    unsigned short* __restrict__ xb,  unsigned short* __restrict__ wqb,
    unsigned short* __restrict__ wkb, unsigned short* __restrict__ wvb,
    unsigned short* __restrict__ wob)
{
  const size_t NX = (size_t)BATCH*SEQ*HID;   // 4M
  const size_t NW = (size_t)HID*HID;         // 1M
  size_t i = ((size_t)blockIdx.x*256 + threadIdx.x)*4;
  const float* src; unsigned short* dst; size_t off;
  if (i < NX) { src = x; dst = xb; off = i; }
  else {
    size_t j = i - NX; int w = (int)(j >> 20); off = j & (NW-1);
    if      (w==0){ src=wq; dst=wqb; }
    else if (w==1){ src=wk; dst=wkb; }
    else if (w==2){ src=wv; dst=wvb; }
    else          { src=wo; dst=wob; }
  }
  float4 v = *(const float4*)(src+off);
  uint2 p;
  p.x = (unsigned)f2bf(v.x) | ((unsigned)f2bf(v.y)<<16);
  p.y = (unsigned)f2bf(v.z) | ((unsigned)f2bf(v.w)<<16);
  *(uint2*)(dst+off) = p;
}

// -------- fused QKV GEMM: BK=32, double-buffered prefetch, 1 barrier/K-step,
// chunk-XOR-swizzled staging/reads, LDS-transpose coalesced epilogue.
// Q/K: head-major [bh][t][d] bf16. V: transposed store DIRECTLY to VhT [bh][d][t].
// Q output pre-scaled by 0.125*log2(e) (softmax scale + exp2 conversion folded).
__global__ __launch_bounds__(256) void gemm_qkv(
    const unsigned short* __restrict__ A,
    const unsigned short* __restrict__ Bq,
    const unsigned short* __restrict__ Bk,
    const unsigned short* __restrict__ Bv,
    unsigned short* __restrict__ Qh,
    unsigned short* __restrict__ Kh,
    unsigned short* __restrict__ VhT)
{
  __shared__ unsigned short S[16384];  // A dbuf [2][128][32] @0; B dbuf [2][128][32] @8192
  const int tid = threadIdx.x;
  const int w = tid >> 6, lane = tid & 63, l15 = lane & 15, quad = lane >> 4;
  const int wm = (w >> 1)*64, wn = (w & 1)*64;
  const int bm = blockIdx.y*128;
  const int which = blockIdx.x >> 3;           // 0=Q 1=K 2=V
  const int bn = (blockIdx.x & 7)*128;
  const unsigned short* B = which==0 ? Bq : (which==1 ? Bk : Bv);
  unsigned short* C       = which==0 ? Qh : (which==1 ? Kh : VhT);
  const float cscale      = which==0 ? 0.18033688011112042f : 1.0f;
  const int lrow = lane >> 2;
  const int lcs = (((lane & 3) ^ ((lane >> 3) & 3))) * 8;   // pre-swizzled src chunk
  const int qsw = (quad ^ ((l15 >> 1) & 3)) * 8;            // swizzled read chunk

  f32x4 acc[4][4] = {};

  // prologue: stage K-tile 0 into buffer 0
  {
    #pragma unroll
    for (int p=0;p<2;p++){
      int c = w*2 + p;                 // 0..7: rows c*16..c*16+15
      gll(&A[(size_t)(bm + c*16 + lrow)*HID + lcs], &S[c*512]);
      gll(&B[(size_t)(bn + c*16 + lrow)*HID + lcs], &S[8192 + c*512]);
    }
  }
  __syncthreads();

  int cur = 0;
  for (int kb=0; kb<32; ++kb){
    // prefetch next K-tile into the other buffer; latency hides under compute
    if (kb < 31){
      unsigned short* Ad = S + (cur^1)*4096;
      unsigned short* Bd = S + 8192 + (cur^1)*4096;
      #pragma unroll
      for (int p=0;p<2;p++){
        int c = w*2 + p;
        gll(&A[(size_t)(bm + c*16 + lrow)*HID + (kb+1)*32 + lcs], &Ad[c*512]);
        gll(&B[(size_t)(bn + c*16 + lrow)*HID + (kb+1)*32 + lcs], &Bd[c*512]);
      }
    }
    const unsigned short* Ac = S + cur*4096;
    const unsigned short* Bc = S + 8192 + cur*4096;
    bf16x8 af[4], bfr[4];
    #pragma unroll
    for (int i=0;i<4;i++) af[i]  = *(const bf16x8*)(&Ac[(wm + i*16 + l15)*32 + qsw]);
    #pragma unroll
    for (int j=0;j<4;j++) bfr[j] = *(const bf16x8*)(&Bc[(wn + j*16 + l15)*32 + qsw]);
    #pragma unroll
    for (int i=0;i<4;i++)
      #pragma unroll
      for (int j=0;j<4;j++)
        acc[i][j] = __builtin_amdgcn_mfma_f32_16x16x32_bf16(af[i], bfr[j], acc[i][j], 0,0,0);
    __syncthreads();   // drains prefetch vmcnt + protects buffer reuse (and epilogue)
    cur ^= 1;
  }

  // epilogue: acc -> XOR-swizzled LDS tile [128][128] bf16
  #pragma unroll
  for (int i=0;i<4;i++)
    #pragma unroll
    for (int j=0;j<4;j++)
      #pragma unroll
      for (int r=0;r<4;r++){
        int row = wm + i*16 + quad*4 + r;        // 0..127 (tile m = t)
        int col = wn + j*16 + l15;               // 0..127 (tile n)
        unsigned off = (unsigned)(row*256 + col*2);
        *(unsigned short*)((char*)S + (off ^ ((unsigned)(row & 7) << 4))) =
            f2bf(acc[i][j][r]*cscale);
      }
  __syncthreads();
  if (which < 2){
    // Q/K: [bh][t][d] with coalesced 16B row stores
    #pragma unroll
    for (int pass=0; pass<8; ++pass){
      int tr    = pass*16 + (tid >> 4);          // tile row
      int hf    = (tid >> 3) & 1;                // which 64-col head-half
      int blkin = tid & 7;                       // 16B block within the 128B run
      unsigned off = (unsigned)(tr*256 + hf*128 + blkin*16);
      uint4 v = *(const uint4_ma*)((const char*)S + (off ^ ((unsigned)(tr & 7) << 4)));
      int m = bm + tr, b = m >> 11, t = m & (SEQ-1);
      int h = (bn >> 6) + hf;
      *(uint4*)(&C[(((size_t)(b*NH + h))*SEQ + t)*HD + blkin*8]) = v;
    }
  } else {
    // V: transpose read-out (column walk), store [bh][d][t] runs of 8 t.
    const int b = bm >> 11, tb = bm & (SEQ-1);
    #pragma unroll
    for (int pass=0; pass<8; ++pass){
      int idx  = pass*256 + tid;                 // 0..2047
      int dcol = idx & 127;                      // tile col (d within 2 heads)
      int tc   = idx >> 7;                       // 8-row t chunk 0..15
      unsigned short tmp[8];
      #pragma unroll
      for (int j=0;j<8;j++){
        int r = tc*8 + j;                        // r&7 == j
        unsigned off = (unsigned)(r*256 + dcol*2) ^ ((unsigned)j << 4);
        tmp[j] = *(const unsigned short*)((const char*)S + off);
      }
      int hh = (bn >> 6) + (dcol >> 6);
      int d  = dcol & 63;
      *(uint4*)(&C[(((size_t)(b*NH + hh))*HD + d)*SEQ + tb + tc*8]) = *(uint4_ma*)tmp;
    }
  }
}

// -------- output projection v2: BK=32, double-buffered prefetch, 1 barrier/K-step,
// chunk-XOR-swizzled staging/reads, 128x64 tiles, fp32 out --------
__global__ __launch_bounds__(256) void gemm_out(
    const unsigned short* __restrict__ A,
    const unsigned short* __restrict__ B,
    float* __restrict__ C)
{
  __shared__ unsigned short S[12288];  // A dbuf [2][128][32] @0; B dbuf [2][64][32] @8192
  const int tid = threadIdx.x;
  const int w = tid >> 6, lane = tid & 63, l15 = lane & 15, quad = lane >> 4;
  const int wm = (w >> 1)*64, wn = (w & 1)*32;
  const int bm = blockIdx.y*128, bn = blockIdx.x*64;
  const int lrow = lane >> 2;
  const int lcs = (((lane & 3) ^ ((lane >> 3) & 3))) * 8;
  const int qsw = (quad ^ ((l15 >> 1) & 3)) * 8;

  f32x4 acc[4][2] = {};

  // prologue: stage K-tile 0 into buffer 0
  {
    #pragma unroll
    for (int p=0;p<2;p++){
      int c = w*2 + p;                 // 0..7: A rows c*16..c*16+15
      gll(&A[(size_t)(bm + c*16 + lrow)*HID + lcs], &S[c*512]);
    }
    // B: 4 chunks, one per wave
    gll(&B[(size_t)(bn + w*16 + lrow)*HID + lcs], &S[8192 + w*512]);
  }
  __syncthreads();

  int cur = 0;
  for (int kb=0; kb<32; ++kb){
    if (kb < 31){
      unsigned short* Ad = S + (cur^1)*4096;
      unsigned short* Bd = S + 8192 + (cur^1)*2048;
      #pragma unroll
      for (int p=0;p<2;p++){
        int c = w*2 + p;
        gll(&A[(size_t)(bm + c*16 + lrow)*HID + (kb+1)*32 + lcs], &Ad[c*512]);
      }
      gll(&B[(size_t)(bn + w*16 + lrow)*HID + (kb+1)*32 + lcs], &Bd[w*512]);
    }
    const unsigned short* Ac = S + cur*4096;
    const unsigned short* Bc = S + 8192 + cur*2048;
    bf16x8 af[4], bfr[2];
    #pragma unroll
    for (int i=0;i<4;i++) af[i]  = *(const bf16x8*)(&Ac[(wm + i*16 + l15)*32 + qsw]);
    #pragma unroll
    for (int j=0;j<2;j++) bfr[j] = *(const bf16x8*)(&Bc[(wn + j*16 + l15)*32 + qsw]);
    #pragma unroll
    for (int i=0;i<4;i++)
      #pragma unroll
      for (int j=0;j<2;j++)
        acc[i][j] = __builtin_amdgcn_mfma_f32_16x16x32_bf16(af[i], bfr[j], acc[i][j], 0,0,0);
    __syncthreads();   // drains prefetch vmcnt + protects buffer reuse
    cur ^= 1;
  }

  #pragma unroll
  for (int i=0;i<4;i++)
    #pragma unroll
    for (int j=0;j<2;j++)
      #pragma unroll
      for (int r=0;r<4;r++){
        int m = bm + wm + i*16 + quad*4 + r;
        int n = bn + wn + j*16 + l15;
        C[(size_t)m*HID + n] = acc[i][j][r];
      }
}

// -------- flash attention v8: k-parallel wave groups, 32 waves/CU --------------
// 512 thr = 8 waves: group A (w0-3) handles EVEN 32-key tiles, group B (w4-7)
// ODD tiles, same 64 q-rows. No-max softmax makes partials additive: O=OA+OB,
// l=lA+lB, merged through LDS once per block. Total waves 8192 -> 32/CU (2x the
// structural 16-wave ceiling every prior variant hit; TLP is the one variable
// that has ever moved this kernel). KVBLK=32/group; serial stage-then-compute,
// 2 barriers per super-iter (= v3's barrier rate). Swapped QK^T; P scratch
// wave-private 80B-stride rows (pad, no XOR needed); chunk-XOR staging swizzle;
// OCML exp2f. LDS = 16K QP(Q/P/merge union) + 8K K + 8K V = 32768 -> grid-cap
// 4 blocks/CU. VGPR capped <=64 via launch_bounds(512,8).
__global__ __launch_bounds__(512, 8) void attn(
    const unsigned short* __restrict__ Qh,
    const unsigned short* __restrict__ Kh,
    const unsigned short* __restrict__ VhT,
    unsigned short* __restrict__ Ao)
{
  __shared__ unsigned short QP[8192];    // 16KB: Q [2 kc][4 rb][16][32] -> P 8x2KB -> merge f32
  __shared__ unsigned short Ks[4096];    // 8KB: [2 tile][2 kc][2 cb][16][32]
  __shared__ unsigned short Vt[4096];    // 8KB: [2 tile][4 cc][16][32]

  const int bh = blockIdx.x;
  const int y  = blockIdx.y;
  // balanced qb remap (round-4 proven)
  const int a = y & 7, bb = y >> 3;
  const int qb = (bb & 1) ? (7 - a)*4 + bb : a*4 + bb;
  const int tid = threadIdx.x;
  const int w = tid >> 6, lane = tid & 63, l15 = lane & 15, quad = lane >> 4;
  const int g = w >> 2, wq = w & 3;      // k-group, q-row-group
  const int lrow = lane >> 2;
  const int lcs = (((lane & 3) ^ ((lane >> 3) & 3))) * 8;   // pre-swizzled src chunk
  const int qsw = (quad ^ ((l15 >> 1) & 3)) * 8;            // swizzled read chunk

  const size_t base = (size_t)bh * SEQ * HD;
  const unsigned short* Qg  = Qh + base + (size_t)qb*64*HD;
  const unsigned short* Kg  = Kh + base;
  const unsigned short* VTg = VhT + base;                    // [d][t]
  char* Psw = (char*)QP + w*2048;        // wave-private P: 16 rows x 80B stride

  // prologue: stage Q (8 chunks, 1/wave) + super-iter 0 (tiles 0=A, 1=B)
  {
    int rb = w & 3, kc = w >> 2;
    gll(&Qg[(size_t)(rb*16 + lrow)*HD + kc*32 + lcs], &QP[kc*2048 + rb*512]);
  }
  #pragma unroll
  for (int p=0;p<2;p++){
    int c = w*2 + p;                     // 0..15
    if (c < 8){                          // K: tile tt, chunk cc -> (kc, cb)
      int tt = c >> 2, cc = c & 3, kc = cc >> 1, cb = cc & 1;
      gll(&Kg[(size_t)(tt*32 + cb*16 + lrow)*HD + kc*32 + lcs],
          &Ks[tt*2048 + kc*1024 + cb*512]);
    } else {                             // V: tile tt, d-rowblk cc
      int tt = (c >> 2) & 1, cc = c & 3;
      gll(&VTg[(size_t)(cc*16 + lrow)*SEQ + tt*32 + lcs],
          &Vt[tt*2048 + cc*512]);
    }
  }
  __syncthreads();
  bf16x8 qfrag[2];
  #pragma unroll
  for (int kc=0;kc<2;kc++)
    qfrag[kc] = *(const bf16x8*)(&QP[kc*2048 + (wq*16 + l15)*32 + qsw]);
  __syncthreads();   // all qfrag reads done before QP is reused as P scratch

  f32x4 lacc = {0.f, 0.f, 0.f, 0.f};
  f32x4 oacc[4] = {};
  const int qrow = qb*64 + wq*16 + l15;  // this lane's q row (swapped layout: q = l15)

  for (int si=0; si<=qb; ++si){
    const int kt = 2*si + g;             // this group's 32-key tile

    // QK^T swapped: s = K·Q^T = S^T; lane holds t = kt*32+cb*16+quad*4+r, q = l15
    f32x4 s[2] = {};
    #pragma unroll
    for (int cb=0;cb<2;cb++)
      #pragma unroll
      for (int kc=0;kc<2;kc++){
        bf16x8 kfr = *(const bf16x8*)(&Ks[g*2048 + kc*1024 + (cb*16 + l15)*32 + qsw]);
        s[cb] = __builtin_amdgcn_mfma_f32_16x16x32_bf16(kfr, qfrag[kc], s[cb], 0,0,0);
      }
    // mask only on the diagonal super-iter (both groups' last tile)
    if (si == qb){
      #pragma unroll
      for (int cb=0;cb<2;cb++)
        #pragma unroll
        for (int r=0;r<4;r++){
          int t = kt*32 + cb*16 + quad*4 + r;
          if (t > qrow) s[cb][r] = -1e30f;
        }
    }
    // p = exp2(s') (no max-subtraction; implicit scale cancels in O/l)
    #pragma unroll
    for (int cb=0;cb<2;cb++)
      #pragma unroll
      for (int r=0;r<4;r++)
        s[cb][r] = exp2f(s[cb][r]);
    lacc += s[0] + s[1];

    // P -> bf16 packed pairs -> wave-private LDS rows (80B stride, ~2-way banks)
    #pragma unroll
    for (int cb=0;cb<2;cb++){
      uint2 d2;
      d2.x = cvtpk_bf16(s[cb][0], s[cb][1]);
      d2.y = cvtpk_bf16(s[cb][2], s[cb][3]);
      *(bf16x4_ma*)(Psw + l15*80 + cb*32 + quad*8) = __builtin_bit_cast(bf16x4, d2);
    }
    asm volatile("" ::: "memory");   // compiler fence: P-writes before P-reads
    bf16x8 pa = *(const bf16x8_ma*)(Psw + l15*80 + quad*16);

    // O += P · V
    #pragma unroll
    for (int db=0;db<4;db++){
      bf16x8 vfr = *(const bf16x8*)(&Vt[g*2048 + (db*16 + l15)*32 + qsw]);
      oacc[db] = __builtin_amdgcn_mfma_f32_16x16x32_bf16(pa, vfr, oacc[db], 0,0,0);
    }

    __syncthreads();                 // all reads of Ks/Vt done
    if (si < qb){
      // stage super-iter si+1 (tiles 2si+2, 2si+3); drain at next barrier
      #pragma unroll
      for (int p=0;p<2;p++){
        int c = w*2 + p;
        if (c < 8){
          int tt = c >> 2, cc = c & 3, kc = cc >> 1, cb = cc & 1;
          gll(&Kg[(size_t)((2*si+2+tt)*32 + cb*16 + lrow)*HD + kc*32 + lcs],
              &Ks[tt*2048 + kc*1024 + cb*512]);
        } else {
          int tt = (c >> 2) & 1, cc = c & 3;
          gll(&VTg[(size_t)(cc*16 + lrow)*SEQ + (size_t)(2*si+2+tt)*32 + lcs],
              &Vt[tt*2048 + cc*512]);
        }
      }
      __syncthreads();               // staged data visible (drains vmcnt)
    }
  }

  // group-local l: lane partial covers its own 8 k-slots per iter
  float l = (lacc[0] + lacc[1]) + (lacc[2] + lacc[3]);
  l += __shfl_xor(l, 16);
  l += __shfl_xor(l, 32);            // every lane: group-partial l for q = l15

  // merge groups through LDS (QP region; P dead after loop-end barrier)
  float* MRG = (float*)QP;           // [4 wq][16 q][64 d] f32 = 16KB
  float* Lb  = (float*)Ks;           // 64 f32
  if (g == 1){
    #pragma unroll
    for (int db=0;db<4;db++)
      #pragma unroll
      for (int r=0;r<4;r++)
        MRG[wq*1024 + (quad*4 + r)*64 + db*16 + l15] = oacc[db][r];
    Lb[wq*16 + l15] = l;             // 4 quads write identical value: benign
  }
  __syncthreads();
  if (g == 0){
    l += Lb[wq*16 + l15];
    #pragma unroll
    for (int db=0;db<4;db++)
      #pragma unroll
      for (int r=0;r<4;r++)
        oacc[db][r] += MRG[wq*1024 + (quad*4 + r)*64 + db*16 + l15];
    float inv[4];
    #pragma unroll
    for (int r=0;r<4;r++)
      inv[r] = 1.0f / __shfl(l, quad*4 + r);   // l for the C-layout row quad*4+r

    const int b = bh >> 4, h = bh & (NH-1);
    #pragma unroll
    for (int db=0;db<4;db++)
      #pragma unroll
      for (int r=0;r<4;r++){
        int t = qb*64 + wq*16 + quad*4 + r;
        int col = h*HD + db*16 + l15;
        Ao[((size_t)b*SEQ + t)*HID + col] = f2bf(oacc[db][r] * inv[r]);
      }
  }
}

extern "C" void kernel_launch(void* const* d_in, const int* in_sizes, int n_in,
                              void* d_out, int out_size, void* d_ws, size_t ws_size,
                              hipStream_t stream)
{
  const float* x  = (const float*)d_in[0];
  const float* Wq = (const float*)d_in[1];
  const float* Wk = (const float*)d_in[2];
  const float* Wv = (const float*)d_in[3];
  const float* Wo = (const float*)d_in[4];

  unsigned short* xb  = (unsigned short*)d_ws;
  unsigned short* wqb = xb  + (size_t)4*1024*1024;
  unsigned short* wkb = wqb + (size_t)1024*1024;
  unsigned short* wvb = wkb + (size_t)1024*1024;
  unsigned short* wob = wvb + (size_t)1024*1024;
  unsigned short* Qh  = wob + (size_t)1024*1024;
  unsigned short* Kh  = Qh  + (size_t)4*1024*1024;
  unsigned short* Vh  = Kh  + (size_t)4*1024*1024;   // unused (kept for layout)
  unsigned short* VhT = Vh  + (size_t)4*1024*1024;
  unsigned short* Ao  = xb;   // x dead after QKV gemm

  cvt_all<<<8192, 256, 0, stream>>>(x, Wq, Wk, Wv, Wo, xb, wqb, wkb, wvb, wob);

  gemm_qkv<<<dim3(24, 32), 256, 0, stream>>>(xb, wqb, wkb, wvb, Qh, Kh, VhT);

  attn<<<dim3(BATCH*NH, SEQ/64), 512, 0, stream>>>(Qh, Kh, VhT, Ao);

  gemm_out<<<dim3(16, 32), 256, 0, stream>>>(Ao, wob, (float*)d_out);
}

// Round 13
// 174.489 us; speedup vs baseline: 1.0836x; 1.0836x over previous
//
#include <hip/hip_runtime.h>
#include <cstdint>
#include <cstddef>

#define HID 1024
#define NH 16
#define HD 64
#define SEQ 2048
#define BATCH 2

typedef __attribute__((ext_vector_type(8))) short bf16x8;
typedef __attribute__((ext_vector_type(4))) short bf16x4;
typedef bf16x8 __attribute__((may_alias)) bf16x8_ma;
typedef bf16x4 __attribute__((may_alias)) bf16x4_ma;
typedef uint4 __attribute__((may_alias)) uint4_ma;
typedef __attribute__((ext_vector_type(4))) float f32x4;

__device__ __forceinline__ unsigned short f2bf(float f){
  unsigned u = __builtin_bit_cast(unsigned, f);
  u += 0x7fffu + ((u >> 16) & 1u);
  return (unsigned short)(u >> 16);
}

__device__ __forceinline__ unsigned cvtpk_bf16(float lo, float hi){
  unsigned r;
  asm("v_cvt_pk_bf16_f32 %0, %1, %2" : "=v"(r) : "v"(lo), "v"(hi));
  return r;
}

// async global->LDS, 16B per lane. LDS dest is wave-uniform base; HW adds lane*16B.
__device__ __forceinline__ void gll(const unsigned short* g, unsigned short* l){
  __builtin_amdgcn_global_load_lds(
      (const __attribute__((address_space(1))) unsigned int*)(g),
      (__attribute__((address_space(3))) unsigned int*)(l),
      16, 0, 0);
}

// Chunk-XOR LDS swizzle: data (row r, 16B-chunk c) lives at chunk-slot c^((r>>1)&3).
// Staging keeps the LDS dest linear (gll requirement) and pre-swizzles the GLOBAL
// source chunk; every fragment read applies the same XOR. 8-way -> 2-way (free).

// ---------------- fp32 -> bf16 conversion of x and the 4 weights ----------------
__global__ __launch_bounds__(256) void cvt_all(
    const float* __restrict__ x,  const float* __restrict__ wq,
    const float* __restrict__ wk, const float* __restrict__ wv,
    const float* __restrict__ wo,
    unsigned short* __restrict__ xb,  unsigned short* __restrict__ wqb,
    unsigned short* __restrict__ wkb, unsigned short* __restrict__ wvb,
    unsigned short* __restrict__ wob)
{
  const size_t NX = (size_t)BATCH*SEQ*HID;   // 4M
  const size_t NW = (size_t)HID*HID;         // 1M
  size_t i = ((size_t)blockIdx.x*256 + threadIdx.x)*4;
  const float* src; unsigned short* dst; size_t off;
  if (i < NX) { src = x; dst = xb; off = i; }
  else {
    size_t j = i - NX; int w = (int)(j >> 20); off = j & (NW-1);
    if      (w==0){ src=wq; dst=wqb; }
    else if (w==1){ src=wk; dst=wkb; }
    else if (w==2){ src=wv; dst=wvb; }
    else          { src=wo; dst=wob; }
  }
  float4 v = *(const float4*)(src+off);
  uint2 p;
  p.x = (unsigned)f2bf(v.x) | ((unsigned)f2bf(v.y)<<16);
  p.y = (unsigned)f2bf(v.z) | ((unsigned)f2bf(v.w)<<16);
  *(uint2*)(dst+off) = p;
}

// -------- fused QKV GEMM: BK=32, double-buffered prefetch, 1 barrier/K-step,
// chunk-XOR-swizzled staging/reads, LDS-transpose coalesced epilogue.
// Q/K: head-major [bh][t][d] bf16. V: transposed store DIRECTLY to VhT [bh][d][t].
// Q output pre-scaled by 0.125*log2(e) (softmax scale + exp2 conversion folded).
__global__ __launch_bounds__(256) void gemm_qkv(
    const unsigned short* __restrict__ A,
    const unsigned short* __restrict__ Bq,
    const unsigned short* __restrict__ Bk,
    const unsigned short* __restrict__ Bv,
    unsigned short* __restrict__ Qh,
    unsigned short* __restrict__ Kh,
    unsigned short* __restrict__ VhT)
{
  __shared__ unsigned short S[16384];  // A dbuf [2][128][32] @0; B dbuf [2][128][32] @8192
  const int tid = threadIdx.x;
  const int w = tid >> 6, lane = tid & 63, l15 = lane & 15, quad = lane >> 4;
  const int wm = (w >> 1)*64, wn = (w & 1)*64;
  const int bm = blockIdx.y*128;
  const int which = blockIdx.x >> 3;           // 0=Q 1=K 2=V
  const int bn = (blockIdx.x & 7)*128;
  const unsigned short* B = which==0 ? Bq : (which==1 ? Bk : Bv);
  unsigned short* C       = which==0 ? Qh : (which==1 ? Kh : VhT);
  const float cscale      = which==0 ? 0.18033688011112042f : 1.0f;
  const int lrow = lane >> 2;
  const int lcs = (((lane & 3) ^ ((lane >> 3) & 3))) * 8;   // pre-swizzled src chunk
  const int qsw = (quad ^ ((l15 >> 1) & 3)) * 8;            // swizzled read chunk

  f32x4 acc[4][4] = {};

  // prologue: stage K-tile 0 into buffer 0
  {
    #pragma unroll
    for (int p=0;p<2;p++){
      int c = w*2 + p;                 // 0..7: rows c*16..c*16+15
      gll(&A[(size_t)(bm + c*16 + lrow)*HID + lcs], &S[c*512]);
      gll(&B[(size_t)(bn + c*16 + lrow)*HID + lcs], &S[8192 + c*512]);
    }
  }
  __syncthreads();

  int cur = 0;
  for (int kb=0; kb<32; ++kb){
    // prefetch next K-tile into the other buffer; latency hides under compute
    if (kb < 31){
      unsigned short* Ad = S + (cur^1)*4096;
      unsigned short* Bd = S + 8192 + (cur^1)*4096;
      #pragma unroll
      for (int p=0;p<2;p++){
        int c = w*2 + p;
        gll(&A[(size_t)(bm + c*16 + lrow)*HID + (kb+1)*32 + lcs], &Ad[c*512]);
        gll(&B[(size_t)(bn + c*16 + lrow)*HID + (kb+1)*32 + lcs], &Bd[c*512]);
      }
    }
    const unsigned short* Ac = S + cur*4096;
    const unsigned short* Bc = S + 8192 + cur*4096;
    bf16x8 af[4], bfr[4];
    #pragma unroll
    for (int i=0;i<4;i++) af[i]  = *(const bf16x8*)(&Ac[(wm + i*16 + l15)*32 + qsw]);
    #pragma unroll
    for (int j=0;j<4;j++) bfr[j] = *(const bf16x8*)(&Bc[(wn + j*16 + l15)*32 + qsw]);
    #pragma unroll
    for (int i=0;i<4;i++)
      #pragma unroll
      for (int j=0;j<4;j++)
        acc[i][j] = __builtin_amdgcn_mfma_f32_16x16x32_bf16(af[i], bfr[j], acc[i][j], 0,0,0);
    __syncthreads();   // drains prefetch vmcnt + protects buffer reuse (and epilogue)
    cur ^= 1;
  }

  // epilogue: acc -> XOR-swizzled LDS tile [128][128] bf16
  #pragma unroll
  for (int i=0;i<4;i++)
    #pragma unroll
    for (int j=0;j<4;j++)
      #pragma unroll
      for (int r=0;r<4;r++){
        int row = wm + i*16 + quad*4 + r;        // 0..127 (tile m = t)
        int col = wn + j*16 + l15;               // 0..127 (tile n)
        unsigned off = (unsigned)(row*256 + col*2);
        *(unsigned short*)((char*)S + (off ^ ((unsigned)(row & 7) << 4))) =
            f2bf(acc[i][j][r]*cscale);
      }
  __syncthreads();
  if (which < 2){
    // Q/K: [bh][t][d] with coalesced 16B row stores
    #pragma unroll
    for (int pass=0; pass<8; ++pass){
      int tr    = pass*16 + (tid >> 4);          // tile row
      int hf    = (tid >> 3) & 1;                // which 64-col head-half
      int blkin = tid & 7;                       // 16B block within the 128B run
      unsigned off = (unsigned)(tr*256 + hf*128 + blkin*16);
      uint4 v = *(const uint4_ma*)((const char*)S + (off ^ ((unsigned)(tr & 7) << 4)));
      int m = bm + tr, b = m >> 11, t = m & (SEQ-1);
      int h = (bn >> 6) + hf;
      *(uint4*)(&C[(((size_t)(b*NH + h))*SEQ + t)*HD + blkin*8]) = v;
    }
  } else {
    // V: transpose read-out (column walk), store [bh][d][t] runs of 8 t.
    const int b = bm >> 11, tb = bm & (SEQ-1);
    #pragma unroll
    for (int pass=0; pass<8; ++pass){
      int idx  = pass*256 + tid;                 // 0..2047
      int dcol = idx & 127;                      // tile col (d within 2 heads)
      int tc   = idx >> 7;                       // 8-row t chunk 0..15
      unsigned short tmp[8];
      #pragma unroll
      for (int j=0;j<8;j++){
        int r = tc*8 + j;                        // r&7 == j
        unsigned off = (unsigned)(r*256 + dcol*2) ^ ((unsigned)j << 4);
        tmp[j] = *(const unsigned short*)((const char*)S + off);
      }
      int hh = (bn >> 6) + (dcol >> 6);
      int d  = dcol & 63;
      *(uint4*)(&C[(((size_t)(b*NH + hh))*HD + d)*SEQ + tb + tc*8]) = *(uint4_ma*)tmp;
    }
  }
}

// -------- output projection v2: BK=32, double-buffered prefetch, 1 barrier/K-step,
// chunk-XOR-swizzled staging/reads, 128x64 tiles, fp32 out --------
__global__ __launch_bounds__(256) void gemm_out(
    const unsigned short* __restrict__ A,
    const unsigned short* __restrict__ B,
    float* __restrict__ C)
{
  __shared__ unsigned short S[12288];  // A dbuf [2][128][32] @0; B dbuf [2][64][32] @8192
  const int tid = threadIdx.x;
  const int w = tid >> 6, lane = tid & 63, l15 = lane & 15, quad = lane >> 4;
  const int wm = (w >> 1)*64, wn = (w & 1)*32;
  const int bm = blockIdx.y*128, bn = blockIdx.x*64;
  const int lrow = lane >> 2;
  const int lcs = (((lane & 3) ^ ((lane >> 3) & 3))) * 8;
  const int qsw = (quad ^ ((l15 >> 1) & 3)) * 8;

  f32x4 acc[4][2] = {};

  // prologue: stage K-tile 0 into buffer 0
  {
    #pragma unroll
    for (int p=0;p<2;p++){
      int c = w*2 + p;                 // 0..7: A rows c*16..c*16+15
      gll(&A[(size_t)(bm + c*16 + lrow)*HID + lcs], &S[c*512]);
    }
    // B: 4 chunks, one per wave
    gll(&B[(size_t)(bn + w*16 + lrow)*HID + lcs], &S[8192 + w*512]);
  }
  __syncthreads();

  int cur = 0;
  for (int kb=0; kb<32; ++kb){
    if (kb < 31){
      unsigned short* Ad = S + (cur^1)*4096;
      unsigned short* Bd = S + 8192 + (cur^1)*2048;
      #pragma unroll
      for (int p=0;p<2;p++){
        int c = w*2 + p;
        gll(&A[(size_t)(bm + c*16 + lrow)*HID + (kb+1)*32 + lcs], &Ad[c*512]);
      }
      gll(&B[(size_t)(bn + w*16 + lrow)*HID + (kb+1)*32 + lcs], &Bd[w*512]);
    }
    const unsigned short* Ac = S + cur*4096;
    const unsigned short* Bc = S + 8192 + cur*2048;
    bf16x8 af[4], bfr[2];
    #pragma unroll
    for (int i=0;i<4;i++) af[i]  = *(const bf16x8*)(&Ac[(wm + i*16 + l15)*32 + qsw]);
    #pragma unroll
    for (int j=0;j<2;j++) bfr[j] = *(const bf16x8*)(&Bc[(wn + j*16 + l15)*32 + qsw]);
    #pragma unroll
    for (int i=0;i<4;i++)
      #pragma unroll
      for (int j=0;j<2;j++)
        acc[i][j] = __builtin_amdgcn_mfma_f32_16x16x32_bf16(af[i], bfr[j], acc[i][j], 0,0,0);
    __syncthreads();   // drains prefetch vmcnt + protects buffer reuse
    cur ^= 1;
  }

  #pragma unroll
  for (int i=0;i<4;i++)
    #pragma unroll
    for (int j=0;j<2;j++)
      #pragma unroll
      for (int r=0;r<4;r++){
        int m = bm + wm + i*16 + quad*4 + r;
        int n = bn + wn + j*16 + l15;
        C[(size_t)m*HID + n] = acc[i][j][r];
      }
}

// -------- flash attention v3 + chunk-XOR swizzle on Q/K/V staging+reads:
// 256 thr (4 waves x 16 rows), 64-row q tiles, 1024 blocks, balanced qb remap,
// 4 blocks/CU. Swapped QK^T; P->bf16 via cvt_pk + may_alias stores to
// XOR-swizzled wave-private scratch + compiler fence; OCML exp2f;
// double-buffered K/V, single vmcnt(0)-barrier per k-block. LDS = 40960B.
// [Plateau config: 6 structural variants (counted-vmcnt, KVBLK=128, QBLK=128,
// k-parallel 32-wave) all measured flat-to-worse; this is the floor.]
__global__ __launch_bounds__(256, 4) void attn(
    const unsigned short* __restrict__ Qh,
    const unsigned short* __restrict__ Kh,
    const unsigned short* __restrict__ VhT,
    unsigned short* __restrict__ Ao)
{
  __shared__ unsigned short QP[4096];      // Q halves [64][32] at 0,2048; later P scratch
  __shared__ unsigned short Ks[2][4096];   // halves [64][32] at 0,2048 per buffer
  __shared__ unsigned short Vt[2][4096];   // key-halves [64 d][32 t] per buffer

  const int bh = blockIdx.x;
  const int y  = blockIdx.y;
  // per-CU balanced qb map: with round-robin placement each CU's 4 blocks sum to 62
  const int a = y & 7, bb = y >> 3;
  const int qb = (bb & 1) ? (7 - a)*4 + bb : a*4 + bb;
  const int tid = threadIdx.x;
  const int w = tid >> 6, lane = tid & 63, l15 = lane & 15, quad = lane >> 4;
  const int lrow = lane >> 2;
  const int lcs = (((lane & 3) ^ ((lane >> 3) & 3))) * 8;   // pre-swizzled src chunk
  const int qsw = (quad ^ ((l15 >> 1) & 3)) * 8;            // swizzled read chunk

  const size_t base = (size_t)bh * SEQ * HD;
  const unsigned short* Qg  = Qh + base + (size_t)qb*64*HD;
  const unsigned short* VTg = VhT + base;                    // [d][t]
  unsigned short* Psw = QP + w*1024;                          // wave-private 2KB
  const unsigned swz = (unsigned)(l15 & 7) << 4;              // P-scratch XOR swizzle

  // stage Q (8 chunks, 2 per wave) + K/V block 0 into buffer 0
  #pragma unroll
  for (int p=0;p<2;p++){
    int c = w*2 + p;                     // 0..7: half=c>>2, rowblk=c&3
    gll(&Qg[(size_t)((c&3)*16 + lrow)*HD + (c>>2)*32 + lcs], &QP[(c>>2)*2048 + (c&3)*512]);
  }
  {
    const unsigned short* Kg = Kh + base;
    if (w < 2){
      #pragma unroll
      for (int p=0;p<4;p++){ int cc = w*4 + p;
        gll(&Kg[(size_t)((cc&3)*16 + lrow)*HD + (cc>>2)*32 + lcs], &Ks[0][(cc>>2)*2048 + (cc&3)*512]); }
    } else {
      #pragma unroll
      for (int p=0;p<4;p++){ int cc = (w-2)*4 + p;
        gll(&VTg[(size_t)((cc&3)*16 + lrow)*SEQ + (cc>>2)*32 + lcs], &Vt[0][(cc>>2)*2048 + (cc&3)*512]); }
    }
  }
  __syncthreads();
  bf16x8 qfrag[2];
  #pragma unroll
  for (int kc=0;kc<2;kc++)
    qfrag[kc] = *(const bf16x8*)(&QP[kc*2048 + (w*16 + l15)*32 + qsw]);
  __syncthreads();   // all qfrag reads done before QP is reused as P scratch

  f32x4 lacc = {0.f, 0.f, 0.f, 0.f};
  f32x4 oacc[4] = {};
  const int qrow = qb*64 + w*16 + l15;   // this lane's q row (swapped layout: q = l15)
  int cur = 0;

  for (int kb=0; kb<=qb; ++kb){
    // prefetch next K/V block into the other buffer (latency hides under compute)
    if (kb < qb){
      const unsigned short* Kg2 = Kh + base + (size_t)(kb+1)*64*HD;
      unsigned short* Kd = Ks[cur^1];
      unsigned short* Vd = Vt[cur^1];
      if (w < 2){
        #pragma unroll
        for (int p=0;p<4;p++){ int cc = w*4 + p;
          gll(&Kg2[(size_t)((cc&3)*16 + lrow)*HD + (cc>>2)*32 + lcs], &Kd[(cc>>2)*2048 + (cc&3)*512]); }
      } else {
        #pragma unroll
        for (int p=0;p<4;p++){ int cc = (w-2)*4 + p;
          gll(&VTg[(size_t)((cc&3)*16 + lrow)*SEQ + (size_t)(kb+1)*64 + (cc>>2)*32 + lcs], &Vd[(cc>>2)*2048 + (cc&3)*512]); }
      }
    }

    // QK^T swapped: s = K·Q^T = S^T; lane holds t = cb*16+quad*4+r, q = l15
    const unsigned short* Ksc = Ks[cur];
    f32x4 s[4] = {};
    #pragma unroll
    for (int cb=0;cb<4;cb++)
      #pragma unroll
      for (int kc=0;kc<2;kc++){
        bf16x8 kfr = *(const bf16x8*)(&Ksc[kc*2048 + (cb*16 + l15)*32 + qsw]);
        s[cb] = __builtin_amdgcn_mfma_f32_16x16x32_bf16(kfr, qfrag[kc], s[cb], 0,0,0);
      }

    // mask only on the diagonal block
    if (kb == qb){
      #pragma unroll
      for (int cb=0;cb<4;cb++)
        #pragma unroll
        for (int r=0;r<4;r++){
          int t = kb*64 + cb*16 + quad*4 + r;
          if (t > qrow) s[cb][r] = -1e30f;
        }
    }
    // p = exp2(s') (no max-subtraction; implicit scale cancels in O/l)
    #pragma unroll
    for (int cb=0;cb<4;cb++)
      #pragma unroll
      for (int r=0;r<4;r++)
        s[cb][r] = exp2f(s[cb][r]);
    lacc += (s[0] + s[1]) + (s[2] + s[3]);

    // P -> bf16 packed pairs (k-contiguous in lane) -> swizzled wave-private LDS
    #pragma unroll
    for (int cb=0;cb<4;cb++){
      uint2 d2;
      d2.x = cvtpk_bf16(s[cb][0], s[cb][1]);
      d2.y = cvtpk_bf16(s[cb][2], s[cb][3]);
      *(bf16x4_ma*)((char*)Psw + (((unsigned)(l15*128 + cb*32 + quad*8)) ^ swz)) =
          __builtin_bit_cast(bf16x4, d2);
    }
    asm volatile("" ::: "memory");   // compiler fence: P-writes before P-reads
    bf16x8 pa[2];
    #pragma unroll
    for (int kc=0;kc<2;kc++)
      pa[kc] = *(const bf16x8_ma*)((const char*)Psw + (((unsigned)(l15*128 + kc*64 + quad*16)) ^ swz));

    // O += P · V
    const unsigned short* Vtc = Vt[cur];
    #pragma unroll
    for (int db=0;db<4;db++)
      #pragma unroll
      for (int kc=0;kc<2;kc++){
        bf16x8 vfr = *(const bf16x8*)(&Vtc[kc*2048 + (db*16 + l15)*32 + qsw]);
        oacc[db] = __builtin_amdgcn_mfma_f32_16x16x32_bf16(pa[kc], vfr, oacc[db], 0,0,0);
      }

    if (kb < qb) __syncthreads();   // drains prefetch vmcnt + protects buffer reuse
    cur ^= 1;
  }

  // epilogue: l = rowsum(P) — lane partial covers its own 16 k-slots
  float l = (lacc[0] + lacc[1]) + (lacc[2] + lacc[3]);
  l += __shfl_xor(l, 16);
  l += __shfl_xor(l, 32);          // now every lane holds l for q = its l15
  float inv[4];
  #pragma unroll
  for (int r=0;r<4;r++)
    inv[r] = 1.0f / __shfl(l, quad*4 + r);   // l for the C-layout row quad*4+r

  const int b = bh >> 4, h = bh & (NH-1);
  #pragma unroll
  for (int db=0;db<4;db++)
    #pragma unroll
    for (int r=0;r<4;r++){
      int t = qb*64 + w*16 + quad*4 + r;
      int col = h*HD + db*16 + l15;
      Ao[((size_t)b*SEQ + t)*HID + col] = f2bf(oacc[db][r] * inv[r]);
    }
}

extern "C" void kernel_launch(void* const* d_in, const int* in_sizes, int n_in,
                              void* d_out, int out_size, void* d_ws, size_t ws_size,
                              hipStream_t stream)
{
  const float* x  = (const float*)d_in[0];
  const float* Wq = (const float*)d_in[1];
  const float* Wk = (const float*)d_in[2];
  const float* Wv = (const float*)d_in[3];
  const float* Wo = (const float*)d_in[4];

  unsigned short* xb  = (unsigned short*)d_ws;
  unsigned short* wqb = xb  + (size_t)4*1024*1024;
  unsigned short* wkb = wqb + (size_t)1024*1024;
  unsigned short* wvb = wkb + (size_t)1024*1024;
  unsigned short* wob = wvb + (size_t)1024*1024;
  unsigned short* Qh  = wob + (size_t)1024*1024;
  unsigned short* Kh  = Qh  + (size_t)4*1024*1024;
  unsigned short* Vh  = Kh  + (size_t)4*1024*1024;   // unused (kept for layout)
  unsigned short* VhT = Vh  + (size_t)4*1024*1024;
  unsigned short* Ao  = xb;   // x dead after QKV gemm

  cvt_all<<<8192, 256, 0, stream>>>(x, Wq, Wk, Wv, Wo, xb, wqb, wkb, wvb, wob);

  gemm_qkv<<<dim3(24, 32), 256, 0, stream>>>(xb, wqb, wkb, wvb, Qh, Kh, VhT);

  attn<<<dim3(BATCH*NH, SEQ/64), 256, 0, stream>>>(Qh, Kh, VhT, Ao);

  gemm_out<<<dim3(16, 32), 256, 0, stream>>>(Ao, wob, (float*)d_out);
}